// Round 1
// baseline (482.133 us; speedup 1.0000x reference)
//
#include <hip/hip_runtime.h>

// GAE: h1 = relu(spmm(X@W1)); h2 = relu(spmm(h1@W2)); Z = spmm(h2@W3);
// A = sigmoid(Z @ Z^T).  Outputs: [A (12288x12288), Z (12288x16)] fp32, concat.

constexpr int NN = 12288;   // nodes
constexpr int NE = 393216;  // edges
constexpr int KD = 1433;    // input dim
// H1 = 32, H2 = 16

// ---------------- GEMM1: X[NN,1433] @ W1[1433,32] -> out[NN,32] ----------------
// thread = (row, col); X row value broadcast across the 32 col-lanes (L1 hit),
// W1 row (128B) shared by all row-groups (L1 hit).
__global__ __launch_bounds__(256) void gemm1(const float* __restrict__ X,
                                             const float* __restrict__ W,
                                             float* __restrict__ out) {
    int tid = blockIdx.x * 256 + threadIdx.x;
    int row = tid >> 5, col = tid & 31;
    const float* xr = X + (size_t)row * KD;
    float acc = 0.f;
    int k = 0;
    for (; k + 8 <= KD; k += 8) {
        float a0 = xr[k + 0], a1 = xr[k + 1], a2 = xr[k + 2], a3 = xr[k + 3];
        float a4 = xr[k + 4], a5 = xr[k + 5], a6 = xr[k + 6], a7 = xr[k + 7];
        acc += a0 * W[(k + 0) * 32 + col];
        acc += a1 * W[(k + 1) * 32 + col];
        acc += a2 * W[(k + 2) * 32 + col];
        acc += a3 * W[(k + 3) * 32 + col];
        acc += a4 * W[(k + 4) * 32 + col];
        acc += a5 * W[(k + 5) * 32 + col];
        acc += a6 * W[(k + 6) * 32 + col];
        acc += a7 * W[(k + 7) * 32 + col];
    }
    for (; k < KD; ++k) acc += xr[k] * W[k * 32 + col];
    out[(size_t)row * 32 + col] = acc;
}

// ---------------- SpMM scatter: out[row[e]] += val[e] * in[col[e]] ----------------
// W threads per edge (W = feature width, power of 2). Atomic accumulate; the
// accumulator (<=1.5MB) is L2-resident.
template <int W>
__global__ __launch_bounds__(256) void spmm(const float* __restrict__ in,
                                            float* __restrict__ out,
                                            const float* __restrict__ ev,
                                            const int* __restrict__ er,
                                            const int* __restrict__ ec) {
    int tid = blockIdx.x * 256 + threadIdx.x;
    int e = tid / W, c = tid % W;  // W is power of two -> shifts
    float v = ev[e];
    int r = er[e], s = ec[e];
    atomicAdd(&out[(size_t)r * W + c], v * in[(size_t)s * W + c]);
}

// ---------------- small GEMM: relu(in[NN,Ci]) @ Wm[Ci,Co] -> out[NN,Co] ----------------
template <int Ci, int Co, bool RELU_IN>
__global__ __launch_bounds__(256) void gemm_small(const float* __restrict__ in,
                                                  const float* __restrict__ Wm,
                                                  float* __restrict__ out) {
    __shared__ float w[Ci * Co];
    for (int i = threadIdx.x; i < Ci * Co; i += 256) w[i] = Wm[i];
    __syncthreads();
    int tid = blockIdx.x * 256 + threadIdx.x;
    int row = tid / Co, col = tid % Co;
    float acc = 0.f;
#pragma unroll
    for (int k = 0; k < Ci; ++k) {
        float v = in[(size_t)row * Ci + k];
        if (RELU_IN) v = fmaxf(v, 0.f);
        acc += v * w[k * Co + col];
    }
    out[(size_t)row * Co + col] = acc;
}

// ---------------- decode: A[i,j] = sigmoid(dot16(Z[i], Z[j])) ----------------
// 64x64 tile per 256-thread block; Z tiles staged in padded LDS (stride 17:
// 2-way bank aliasing = free). Each thread: 16 outputs, wave-coalesced stores.
__global__ __launch_bounds__(256) void decode(const float* __restrict__ Z,
                                              float* __restrict__ A) {
    __shared__ float zr[64][17];
    __shared__ float zc[64][17];
    int bi = blockIdx.y, bj = blockIdx.x;
    int tid = threadIdx.x;
    for (int i = tid; i < 64 * 16; i += 256) {
        zr[i >> 4][i & 15] = Z[(size_t)bi * 1024 + i];
        zc[i >> 4][i & 15] = Z[(size_t)bj * 1024 + i];
    }
    __syncthreads();
    int j = tid & 63;       // column within tile (contiguous across the wave)
    int i0 = tid >> 6;      // 0..3
    float zj[16];
#pragma unroll
    for (int k = 0; k < 16; ++k) zj[k] = zc[j][k];
#pragma unroll
    for (int ii = 0; ii < 16; ++ii) {
        int i = ii * 4 + i0;  // wave-uniform row -> zr reads are LDS broadcast
        float acc = 0.f;
#pragma unroll
        for (int k = 0; k < 16; ++k) acc += zr[i][k] * zj[k];
        float s = 1.0f / (1.0f + __expf(-acc));
        A[((size_t)bi * 64 + i) * NN + (size_t)bj * 64 + j] = s;
    }
}

extern "C" void kernel_launch(void* const* d_in, const int* in_sizes, int n_in,
                              void* d_out, int out_size, void* d_ws, size_t ws_size,
                              hipStream_t stream) {
    const float* X  = (const float*)d_in[0];
    const float* W1 = (const float*)d_in[1];
    const float* W2 = (const float*)d_in[2];
    const float* W3 = (const float*)d_in[3];
    const float* ev = (const float*)d_in[4];
    const int*   er = (const int*)d_in[5];
    const int*   ec = (const int*)d_in[6];

    float* A = (float*)d_out;                 // [NN, NN]
    float* Z = A + (size_t)NN * NN;           // [NN, 16]

    float* b0 = (float*)d_ws;                 // [NN, 32]
    float* b1 = b0 + (size_t)NN * 32;         // [NN, 32]
    float* b2 = b1 + (size_t)NN * 32;         // [NN, 32]

    // 1) b0 = X @ W1
    gemm1<<<NN * 32 / 256, 256, 0, stream>>>(X, W1, b0);

    // 2) b1 = spmm(b0)   (h1 = relu(b1) fused into next reader)
    hipMemsetAsync(b1, 0, (size_t)NN * 32 * sizeof(float), stream);
    spmm<32><<<(size_t)NE * 32 / 256, 256, 0, stream>>>(b0, b1, ev, er, ec);

    // 3) b2 = relu(b1) @ W2
    gemm_small<32, 32, true><<<NN * 32 / 256, 256, 0, stream>>>(b1, W2, b2);

    // 4) b0 = spmm(b2)
    hipMemsetAsync(b0, 0, (size_t)NN * 32 * sizeof(float), stream);
    spmm<32><<<(size_t)NE * 32 / 256, 256, 0, stream>>>(b2, b0, ev, er, ec);

    // 5) b1[:, :16] = relu(b0) @ W3
    gemm_small<32, 16, true><<<NN * 16 / 256, 256, 0, stream>>>(b0, W3, b1);

    // 6) Z = spmm(b1)   (accumulated directly into d_out's Z slot)
    hipMemsetAsync(Z, 0, (size_t)NN * 16 * sizeof(float), stream);
    spmm<16><<<(size_t)NE * 16 / 256, 256, 0, stream>>>(b1, Z, ev, er, ec);

    // 7) A = sigmoid(Z @ Z^T)
    dim3 g(NN / 64, NN / 64);
    decode<<<g, 256, 0, stream>>>(Z, A);
}

// Round 3
// 404.389 us; speedup vs baseline: 1.1922x; 1.1922x over previous
//
#include <hip/hip_runtime.h>

// GAE: h1 = relu(spmm(X@W1)); h2 = relu(spmm(h1@W2)); Z = spmm(h2@W3);
// A = sigmoid(Z @ Z^T).  Outputs: [A (12288x12288), Z (12288x16)] fp32, concat.
//
// SpMM strategy: build CSR once per call (count + scan + scatter), then each
// SpMM is a pure gather (no atomics, no accumulator memsets). CSR scratch
// lives in the tail of A, which decode overwrites at the very end.

constexpr int NN = 12288;   // nodes
constexpr int NE = 393216;  // edges
constexpr int KD = 1433;    // input dim

typedef float f32x4 __attribute__((ext_vector_type(4)));

// ---------------- GEMM1: X[NN,1433] @ W1[1433,32] -> out[NN,32] ----------------
__global__ __launch_bounds__(256) void gemm1(const float* __restrict__ X,
                                             const float* __restrict__ W,
                                             float* __restrict__ out) {
    int tid = blockIdx.x * 256 + threadIdx.x;
    int row = tid >> 5, col = tid & 31;
    const float* xr = X + (size_t)row * KD;
    float acc = 0.f;
    int k = 0;
    for (; k + 8 <= KD; k += 8) {
        float a0 = xr[k + 0], a1 = xr[k + 1], a2 = xr[k + 2], a3 = xr[k + 3];
        float a4 = xr[k + 4], a5 = xr[k + 5], a6 = xr[k + 6], a7 = xr[k + 7];
        acc += a0 * W[(k + 0) * 32 + col];
        acc += a1 * W[(k + 1) * 32 + col];
        acc += a2 * W[(k + 2) * 32 + col];
        acc += a3 * W[(k + 3) * 32 + col];
        acc += a4 * W[(k + 4) * 32 + col];
        acc += a5 * W[(k + 5) * 32 + col];
        acc += a6 * W[(k + 6) * 32 + col];
        acc += a7 * W[(k + 7) * 32 + col];
    }
    for (; k < KD; ++k) acc += xr[k] * W[k * 32 + col];
    out[(size_t)row * 32 + col] = acc;
}

// ---------------- CSR build ----------------
__global__ __launch_bounds__(256) void csr_count(const int* __restrict__ er,
                                                 int* __restrict__ cnt) {
    int e = blockIdx.x * 256 + threadIdx.x;
    atomicAdd(&cnt[er[e]], 1);
}

// One block, 1024 threads, 12 rows each (12288 = 1024*12). Hillis-Steele scan.
__global__ __launch_bounds__(1024) void csr_scan(const int* __restrict__ cnt,
                                                 int* __restrict__ ptr,
                                                 int* __restrict__ pos) {
    __shared__ int s[1024];
    int t = threadIdx.x;
    int base = t * 12;
    int loc[12];
    int sum = 0;
#pragma unroll
    for (int i = 0; i < 12; ++i) { loc[i] = sum; sum += cnt[base + i]; }
    s[t] = sum;
    __syncthreads();
    for (int off = 1; off < 1024; off <<= 1) {
        int v = (t >= off) ? s[t - off] : 0;
        __syncthreads();
        s[t] += v;
        __syncthreads();
    }
    int excl = (t == 0) ? 0 : s[t - 1];
#pragma unroll
    for (int i = 0; i < 12; ++i) {
        ptr[base + i] = excl + loc[i];
        pos[base + i] = excl + loc[i];
    }
    if (t == 0) ptr[NN] = NE;
}

__global__ __launch_bounds__(256) void csr_scatter(const float* __restrict__ ev,
                                                   const int* __restrict__ er,
                                                   const int* __restrict__ ec,
                                                   int* __restrict__ pos,
                                                   int* __restrict__ ecol,
                                                   float* __restrict__ eval) {
    int e = blockIdx.x * 256 + threadIdx.x;
    int r = er[e];
    int p = atomicAdd(&pos[r], 1);
    ecol[p] = ec[e];
    eval[p] = ev[e];
}

// ---------------- SpMM gather: out[r,c] = sum_i eval[i] * in[ecol[i], c] ----------------
template <int W>
__global__ __launch_bounds__(256) void spmm_csr(const float* __restrict__ in,
                                                float* __restrict__ out,
                                                const int* __restrict__ ptr,
                                                const int* __restrict__ ecol,
                                                const float* __restrict__ eval) {
    int tid = blockIdx.x * 256 + threadIdx.x;
    int r = tid / W, c = tid % W;
    int b = ptr[r], e = ptr[r + 1];
    float acc = 0.f;
#pragma unroll 2
    for (int i = b; i < e; ++i) {
        acc += eval[i] * in[(size_t)ecol[i] * W + c];
    }
    out[(size_t)r * W + c] = acc;
}

// ---------------- small GEMM: relu(in[NN,Ci]) @ Wm[Ci,Co] -> out[NN,Co] ----------------
template <int Ci, int Co, bool RELU_IN>
__global__ __launch_bounds__(256) void gemm_small(const float* __restrict__ in,
                                                  const float* __restrict__ Wm,
                                                  float* __restrict__ out) {
    __shared__ float w[Ci * Co];
    for (int i = threadIdx.x; i < Ci * Co; i += 256) w[i] = Wm[i];
    __syncthreads();
    int tid = blockIdx.x * 256 + threadIdx.x;
    int row = tid / Co, col = tid % Co;
    float acc = 0.f;
#pragma unroll
    for (int k = 0; k < Ci; ++k) {
        float v = in[(size_t)row * Ci + k];
        if (RELU_IN) v = fmaxf(v, 0.f);
        acc += v * w[k * Co + col];
    }
    out[(size_t)row * Co + col] = acc;
}

// ---------------- decode: A[i,j] = sigmoid(dot16(Z[i], Z[j])) ----------------
// 64x64 tile / 256-thread block. Thread computes 4 rows x 4 consecutive cols;
// stores are native-vector float4, nontemporal (A is a 604MB streaming write).
__global__ __launch_bounds__(256) void decode(const float* __restrict__ Z,
                                              float* __restrict__ A) {
    __shared__ float zr[64][17];
    __shared__ float zc[64][17];
    int bi = blockIdx.y, bj = blockIdx.x;
    int tid = threadIdx.x;
    for (int i = tid; i < 64 * 16; i += 256) {
        zr[i >> 4][i & 15] = Z[(size_t)bi * 1024 + i];
        zc[i >> 4][i & 15] = Z[(size_t)bj * 1024 + i];
    }
    __syncthreads();
    int j4 = (tid & 15) * 4;   // 0,4,...,60
    int i0 = tid >> 4;         // 0..15
    float zj[4][16];
#pragma unroll
    for (int jj = 0; jj < 4; ++jj)
#pragma unroll
        for (int k = 0; k < 16; ++k) zj[jj][k] = zc[j4 + jj][k];
#pragma unroll
    for (int ii = 0; ii < 4; ++ii) {
        int i = ii * 16 + i0;
        f32x4 o;
#pragma unroll
        for (int jj = 0; jj < 4; ++jj) {
            float acc = 0.f;
#pragma unroll
            for (int k = 0; k < 16; ++k) acc += zr[i][k] * zj[jj][k];
            float e = __expf(-acc);
            o[jj] = __fdividef(1.0f, 1.0f + e);
        }
        f32x4* dst = (f32x4*)&A[((size_t)bi * 64 + i) * NN + (size_t)bj * 64 + j4];
        __builtin_nontemporal_store(o, dst);
    }
}

extern "C" void kernel_launch(void* const* d_in, const int* in_sizes, int n_in,
                              void* d_out, int out_size, void* d_ws, size_t ws_size,
                              hipStream_t stream) {
    const float* X  = (const float*)d_in[0];
    const float* W1 = (const float*)d_in[1];
    const float* W2 = (const float*)d_in[2];
    const float* W3 = (const float*)d_in[3];
    const float* ev = (const float*)d_in[4];
    const int*   er = (const int*)d_in[5];
    const int*   ec = (const int*)d_in[6];

    float* A = (float*)d_out;                 // [NN, NN]
    float* Z = A + (size_t)NN * NN;           // [NN, 16]

    float* b0 = (float*)d_ws;                 // [NN, 32]
    float* b1 = b0 + (size_t)NN * 32;         // [NN, 32]
    float* b2 = b1 + (size_t)NN * 32;         // [NN, 32]

    // CSR scratch in the tail of A (decode overwrites it last). 560MB offset,
    // ~3.3MB used, A is 604MB.
    int*   cnt  = (int*)(A + (size_t)140000000);
    int*   ptr  = cnt + NN;          // NN+1
    int*   pos  = ptr + NN + 1;      // NN
    int*   ecol = pos + NN;          // NE
    float* eval = (float*)(ecol + NE);  // NE

    // --- CSR build (once; reused by all 3 SpMMs) ---
    (void)hipMemsetAsync(cnt, 0, NN * sizeof(int), stream);
    csr_count<<<NE / 256, 256, 0, stream>>>(er, cnt);
    csr_scan<<<1, 1024, 0, stream>>>(cnt, ptr, pos);
    csr_scatter<<<NE / 256, 256, 0, stream>>>(ev, er, ec, pos, ecol, eval);

    // 1) b0 = X @ W1
    gemm1<<<NN * 32 / 256, 256, 0, stream>>>(X, W1, b0);

    // 2) b1 = spmm(b0)
    spmm_csr<32><<<NN * 32 / 256, 256, 0, stream>>>(b0, b1, ptr, ecol, eval);

    // 3) b2 = relu(b1) @ W2
    gemm_small<32, 32, true><<<NN * 32 / 256, 256, 0, stream>>>(b1, W2, b2);

    // 4) b0 = spmm(b2)
    spmm_csr<32><<<NN * 32 / 256, 256, 0, stream>>>(b2, b0, ptr, ecol, eval);

    // 5) b1[:, :16] = relu(b0) @ W3
    gemm_small<32, 16, true><<<NN * 16 / 256, 256, 0, stream>>>(b0, W3, b1);

    // 6) Z = spmm(b1)
    spmm_csr<16><<<NN * 16 / 256, 256, 0, stream>>>(b1, Z, ptr, ecol, eval);

    // 7) A = sigmoid(Z @ Z^T)
    dim3 g(NN / 64, NN / 64);
    decode<<<g, 256, 0, stream>>>(Z, A);
}